// Round 1
// baseline (340.378 us; speedup 1.0000x reference)
//
#include <hip/hip_runtime.h>
#include <hip/hip_bf16.h>

// NeighbourLoss: mean((||p_n - p_idx||^2 - orig)^2) * 1e5
// N = 1<<20 points, K = 16 neighbours.

#define NPTS 1048576
#define KNBR 16
#define BLOCK 256

__global__ __launch_bounds__(BLOCK) void nbr_loss_partial(
    const float* __restrict__ points,
    const int* __restrict__ nbr,
    const float* __restrict__ orig,
    double* __restrict__ accum) {

    int n = blockIdx.x * BLOCK + threadIdx.x;

    float local = 0.0f;
    // every thread in-range since grid exactly covers NPTS (power of 2)
    {
        const float px = points[3 * n + 0];
        const float py = points[3 * n + 1];
        const float pz = points[3 * n + 2];

        const int4*   nb4 = (const int4*)(nbr  + (size_t)n * KNBR);
        const float4* od4 = (const float4*)(orig + (size_t)n * KNBR);

#pragma unroll
        for (int v = 0; v < 4; ++v) {
            int4   id = nb4[v];
            float4 od = od4[v];
            int   ids[4] = { id.x, id.y, id.z, id.w };
            float ods[4] = { od.x, od.y, od.z, od.w };
#pragma unroll
            for (int j = 0; j < 4; ++j) {
                const float* q = points + (size_t)3 * (size_t)ids[j];
                float dx = px - q[0];
                float dy = py - q[1];
                float dz = pz - q[2];
                float curr = dx * dx + dy * dy + dz * dz;
                float e = curr - ods[j];
                local = fmaf(e, e, local);
            }
        }
    }

    // wave-64 shuffle reduction
#pragma unroll
    for (int off = 32; off > 0; off >>= 1)
        local += __shfl_down(local, off, 64);

    __shared__ float wsum[BLOCK / 64];
    int lane = threadIdx.x & 63;
    int wid  = threadIdx.x >> 6;
    if (lane == 0) wsum[wid] = local;
    __syncthreads();

    if (threadIdx.x == 0) {
        float s = 0.0f;
#pragma unroll
        for (int w = 0; w < BLOCK / 64; ++w) s += wsum[w];
        atomicAdd(accum, (double)s);
    }
}

__global__ void nbr_loss_finalize(const double* __restrict__ accum,
                                  float* __restrict__ out) {
    double mean = accum[0] / (double)((long long)NPTS * KNBR);
    out[0] = (float)(mean * 100000.0);
}

extern "C" void kernel_launch(void* const* d_in, const int* in_sizes, int n_in,
                              void* d_out, int out_size, void* d_ws, size_t ws_size,
                              hipStream_t stream) {
    const float* points = (const float*)d_in[0];
    const int*   nbr    = (const int*)d_in[1];
    const float* orig   = (const float*)d_in[2];
    float* out = (float*)d_out;
    double* accum = (double*)d_ws;

    // ws is poisoned 0xAA before every timed launch — zero our accumulator.
    hipMemsetAsync(accum, 0, sizeof(double), stream);

    dim3 grid(NPTS / BLOCK);
    nbr_loss_partial<<<grid, BLOCK, 0, stream>>>(points, nbr, orig, accum);
    nbr_loss_finalize<<<1, 1, 0, stream>>>(accum, out);
}